// Round 2
// baseline (51.988 us; speedup 1.0000x reference)
//
#include <hip/hip_runtime.h>
#include <stdint.h>
#include <math.h>

#define BN 16
#define LATN 64
#define STATSN 7
#define ZN 71
#define HN 128
#define H2N 256
#define NNODE 256
#define NPAIR 32640            // N*(N-1)/2
#define NQ 522240              // BN*NPAIR (pairs total); flat bits count = 2*NQ

// ---------------- Threefry-2x32, 20 rounds, key = (0, 42) ----------------
__device__ __forceinline__ void tf2x32(uint32_t x0, uint32_t x1,
                                       uint32_t& o0, uint32_t& o1) {
    const uint32_t ks0 = 0u, ks1 = 42u, ks2 = 0x1BD11BF0u;  // 0^42^0x1BD11BDA
    x0 += ks0; x1 += ks1;
#define TFRND(r) { x0 += x1; x1 = (x1 << (r)) | (x1 >> (32 - (r))); x1 ^= x0; }
    TFRND(13) TFRND(15) TFRND(26) TFRND(6)
    x0 += ks1; x1 += ks2 + 1u;
    TFRND(17) TFRND(29) TFRND(16) TFRND(24)
    x0 += ks2; x1 += ks0 + 2u;
    TFRND(13) TFRND(15) TFRND(26) TFRND(6)
    x0 += ks0; x1 += ks1 + 3u;
    TFRND(17) TFRND(29) TFRND(16) TFRND(24)
    x0 += ks1; x1 += ks2 + 4u;
    TFRND(13) TFRND(15) TFRND(26) TFRND(6)
    x0 += ks2; x1 += ks0 + 5u;
#undef TFRND
    o0 = x0; o1 = x1;
}

// partitionable-mode bits for flat index m (hi32(m)=0 for our sizes): o0 ^ o1
__device__ __forceinline__ uint32_t bits_partitionable(uint32_t m) {
    uint32_t o0, o1;
    tf2x32(0u, m, o0, o1);
    return o0 ^ o1;
}

// jax uniform recipe: f = bitcast((bits>>9)|0x3f800000) - 1; u = max(1e-9, f*(1-1e-9)+1e-9)
__device__ __forceinline__ float bits_to_u(uint32_t w) {
    float f = __uint_as_float((w >> 9) | 0x3f800000u) - 1.0f;
    const float mn = 1e-9f;
    return fmaxf(mn, f * (1.0f - mn) + mn);
}

// ---------------- per-batch logits ----------------
__device__ __forceinline__ double block_reduce(double v, double* red) {
    const int t = threadIdx.x;
    red[t] = v;
    __syncthreads();
#pragma unroll
    for (int s = 128; s > 0; s >>= 1) {
        if (t < s) red[t] += red[t + s];
        __syncthreads();
    }
    double r = red[0];
    __syncthreads();
    return r;
}

__global__ __launch_bounds__(256) void logits_kernel(
    const float* __restrict__ x, const float* __restrict__ st,
    const float* __restrict__ ipw, const float* __restrict__ ipb,
    const float* __restrict__ ipg, const float* __restrict__ ipbb,
    const float* __restrict__ drw, const float* __restrict__ drb,
    const float* __restrict__ drg, const float* __restrict__ drbb,
    const float* __restrict__ r1w, const float* __restrict__ r1b,
    const float* __restrict__ r2w, const float* __restrict__ r2b,
    const float* __restrict__ n1g, const float* __restrict__ n1b,
    const float* __restrict__ n2g, const float* __restrict__ n2b,
    const float* __restrict__ e1w, const float* __restrict__ e1b,
    const float* __restrict__ eg,  const float* __restrict__ eb,
    const float* __restrict__ e2w, const float* __restrict__ e2b,
    float* __restrict__ out_logits)
{
    __shared__ float A[H2N];
    __shared__ float Bv[H2N];
    __shared__ double red[H2N];
    __shared__ float z[ZN + 1];
    const int t = threadIdx.x;
    const int b = blockIdx.x;

    if (t < LATN) z[t] = x[b * LATN + t];
    else if (t < ZN) z[t] = st[b * STATSN + (t - LATN)];
    __syncthreads();

    // ---- input_proj: [71] @ [71,256], relu, LN(256)
    {
        double acc = 0.0;
        for (int k = 0; k < ZN; ++k)
            acc = fma((double)z[k], (double)ipw[k * H2N + t], acc);
        float v = fmaxf((float)acc + ipb[t], 0.0f);
        double s = block_reduce((double)v, red);
        float m = (float)s * (1.0f / 256.0f);
        float d = v - m;
        double s2 = block_reduce((double)(d * d), red);
        float var = (float)s2 * (1.0f / 256.0f);
        float r = d / sqrtf(var + 1e-5f);
        A[t] = r * ipg[t] + ipbb[t];
    }
    __syncthreads();

    // ---- dim_reduce: [256] @ [256,128], relu, LN(128)  -> Bv[0..127]
    {
        bool act = t < HN;
        float v = 0.0f;
        if (act) {
            double acc = 0.0;
            for (int k = 0; k < H2N; ++k)
                acc = fma((double)A[k], (double)drw[k * HN + t], acc);
            v = fmaxf((float)acc + drb[t], 0.0f);
        }
        double s = block_reduce(act ? (double)v : 0.0, red);
        float m = (float)s * (1.0f / 128.0f);
        float d = v - m;
        double s2 = block_reduce(act ? (double)(d * d) : 0.0, red);
        float var = (float)s2 * (1.0f / 128.0f);
        float r = d / sqrtf(var + 1e-5f);
        if (act) Bv[t] = r * drg[t] + drbb[t];
    }
    __syncthreads();

    // ---- residual blocks: h = h + 0.1*(mlp(h) + h)
    for (int l = 0; l < 2; ++l) {
        const float* w1 = r1w + l * HN * HN;
        const float* b1 = r1b + l * HN;
        const float* w2 = r2w + l * HN * HN;
        const float* b2 = r2b + l * HN;
        const float* g1 = n1g + l * HN;
        const float* c1 = n1b + l * HN;
        const float* g2 = n2g + l * HN;
        const float* c2 = n2b + l * HN;
        bool act = t < HN;
        float hval = act ? Bv[t] : 0.0f;
        // LN1
        double s = block_reduce(act ? (double)hval : 0.0, red);
        float m = (float)s * (1.0f / 128.0f);
        float d = hval - m;
        double s2 = block_reduce(act ? (double)(d * d) : 0.0, red);
        float var = (float)s2 * (1.0f / 128.0f);
        float r1v = d / sqrtf(var + 1e-5f);
        if (act) A[t] = r1v * g1[t] + c1[t];
        __syncthreads();
        // lin1 + relu
        float rr = 0.0f;
        if (act) {
            double acc = 0.0;
            for (int k = 0; k < HN; ++k)
                acc = fma((double)A[k], (double)w1[k * HN + t], acc);
            rr = fmaxf((float)acc + b1[t], 0.0f);
        }
        // LN2
        s = block_reduce(act ? (double)rr : 0.0, red);
        m = (float)s * (1.0f / 128.0f);
        d = rr - m;
        s2 = block_reduce(act ? (double)(d * d) : 0.0, red);
        var = (float)s2 * (1.0f / 128.0f);
        float r2v = d / sqrtf(var + 1e-5f);
        __syncthreads();
        if (act) A[t] = r2v * g2[t] + c2[t];
        __syncthreads();
        // lin2
        float r2o = 0.0f;
        if (act) {
            double acc = 0.0;
            for (int k = 0; k < HN; ++k)
                acc = fma((double)A[k], (double)w2[k * HN + t], acc);
            r2o = (float)acc + b2[t];
        }
        __syncthreads();
        if (act) Bv[t] = hval + 0.1f * (r2o + hval);
        __syncthreads();
    }

    // ---- attention over identical nodes -> exactly uniform 1/256 (exact pow2 scale)
    {
        bool act = t < HN;
        if (act) A[t] = Bv[t] * 0.00390625f;  // h * (1/256), exact
        __syncthreads();
        // e1: edge_in = [hf, hf] (256) @ [256,128], relu, LN(128)
        float ev = 0.0f;
        if (act) {
            double acc = 0.0;
            for (int k = 0; k < H2N; ++k)
                acc = fma((double)A[k & (HN - 1)], (double)e1w[k * HN + t], acc);
            ev = fmaxf((float)acc + e1b[t], 0.0f);
        }
        double s = block_reduce(act ? (double)ev : 0.0, red);
        float m = (float)s * (1.0f / 128.0f);
        float d = ev - m;
        double s2 = block_reduce(act ? (double)(d * d) : 0.0, red);
        float var = (float)s2 * (1.0f / 128.0f);
        float r = d / sqrtf(var + 1e-5f);
        __syncthreads();
        if (act) Bv[t] = r * eg[t] + eb[t];
        __syncthreads();
        // logits = e @ [128,2] + b
        if (t < 2) {
            double acc = 0.0;
            for (int k = 0; k < HN; ++k)
                acc = fma((double)Bv[k], (double)e2w[k * 2 + t], acc);
            out_logits[b * 2 + t] = (float)acc + e2b[t];
        }
    }
}

// ---------------- per-pair gumbel decisions + scatter ----------------
__device__ __forceinline__ int rowbase(int i) { return (i * (2 * NNODE - 1 - i)) >> 1; }

__global__ __launch_bounds__(256) void edges_kernel(const float* __restrict__ lg,
                                                    const float* __restrict__ tptr,
                                                    float* __restrict__ out)
{
    int q = blockIdx.x * blockDim.x + threadIdx.x;
    if (q >= NQ) return;
    // diagonal zeros (poison-safe: every output element is written each call)
    if (q < BN * NNODE) {
        int bb = q >> 8, ii = q & 255;
        out[(bb << 16) | (ii << 8) | ii] = 0.0f;
    }
    float temp = fminf(fmaxf(tptr[0], 0.1f), 2.0f);

    int b = q / NPAIR;
    int p = q - b * NPAIR;
    // decode upper-triangular (i,j) from linear pair index p
    double disc = 261121.0 - 8.0 * (double)p;  // 511^2 - 8p
    int i = (int)((511.0 - sqrt(disc)) * 0.5);
    if (i < 0) i = 0;
    if (i > NNODE - 2) i = NNODE - 2;
    while (rowbase(i + 1) <= p) ++i;
    while (rowbase(i) > p) --i;
    int j = p - rowbase(i) + i + 1;

    // partitionable threefry: flat element m -> bits = xor(threefry2x32((0,42), 0, m))
    uint32_t w0 = bits_partitionable((uint32_t)(2 * q));
    uint32_t w1 = bits_partitionable((uint32_t)(2 * q + 1));

    float u0 = bits_to_u(w0), u1 = bits_to_u(w1);
    float g0 = (float)(-log(-log((double)u0)));
    float g1 = (float)(-log(-log((double)u1)));
    float l0 = lg[2 * b], l1 = lg[2 * b + 1];
    float A0 = (l0 + g0) / temp, A1 = (l1 + g1) / temp;
    // literal fp32 softmax + argmax (ties -> index 0), mirroring the reference
    float mx = fmaxf(A0, A1);
    float e0 = expf(A0 - mx), e1 = expf(A1 - mx);
    float ssum = e0 + e1;
    float y0 = e0 / ssum, y1 = e1 / ssum;
    float xe = (y0 >= y1) ? 1.0f : 0.0f;
    out[(b << 16) | (i << 8) | j] = xe;
    out[(b << 16) | (j << 8) | i] = xe;
}

extern "C" void kernel_launch(void* const* d_in, const int* in_sizes, int n_in,
                              void* d_out, int out_size, void* d_ws, size_t ws_size,
                              hipStream_t stream)
{
    const float* x    = (const float*)d_in[0];
    const float* st   = (const float*)d_in[1];
    const float* ipw  = (const float*)d_in[2];
    const float* ipb  = (const float*)d_in[3];
    const float* ipg  = (const float*)d_in[4];
    const float* ipbb = (const float*)d_in[5];
    const float* drw  = (const float*)d_in[6];
    const float* drb  = (const float*)d_in[7];
    const float* drg  = (const float*)d_in[8];
    const float* drbb = (const float*)d_in[9];
    const float* r1w  = (const float*)d_in[10];
    const float* r1b  = (const float*)d_in[11];
    const float* r2w  = (const float*)d_in[12];
    const float* r2b  = (const float*)d_in[13];
    const float* n1g  = (const float*)d_in[14];
    const float* n1b  = (const float*)d_in[15];
    const float* n2g  = (const float*)d_in[16];
    const float* n2b  = (const float*)d_in[17];
    // d_in[18] attn_w, d_in[19] attn_b: unused (softmax over identical nodes is uniform)
    const float* e1w  = (const float*)d_in[20];
    const float* e1b  = (const float*)d_in[21];
    const float* eg   = (const float*)d_in[22];
    const float* eb   = (const float*)d_in[23];
    const float* e2w  = (const float*)d_in[24];
    const float* e2b  = (const float*)d_in[25];
    const float* temp = (const float*)d_in[26];
    float* out = (float*)d_out;
    float* lg  = (float*)d_ws;   // 32 floats: per-batch logits

    hipLaunchKernelGGL(logits_kernel, dim3(BN), dim3(256), 0, stream,
        x, st, ipw, ipb, ipg, ipbb, drw, drb, drg, drbb,
        r1w, r1b, r2w, r2b, n1g, n1b, n2g, n2b,
        e1w, e1b, eg, eb, e2w, e2b, lg);
    hipLaunchKernelGGL(edges_kernel, dim3((NQ + 255) / 256), dim3(256), 0, stream,
        lg, temp, out);
}

// Round 3
// 43.495 us; speedup vs baseline: 1.1953x; 1.1953x over previous
//
#include <hip/hip_runtime.h>
#include <stdint.h>
#include <math.h>

#define BN 16
#define LATN 64
#define STATSN 7
#define ZN 71
#define HN 128
#define H2N 256
#define NNODE 256
#define NPAIR 32640            // N*(N-1)/2
#define NQ 522240              // BN*NPAIR

// ---------------- Threefry-2x32, 20 rounds, key = (0, 42) ----------------
__device__ __forceinline__ void tf2x32(uint32_t x0, uint32_t x1,
                                       uint32_t& o0, uint32_t& o1) {
    const uint32_t ks0 = 0u, ks1 = 42u, ks2 = 0x1BD11BF0u;  // 0^42^0x1BD11BDA
    x0 += ks0; x1 += ks1;
#define TFRND(r) { x0 += x1; x1 = (x1 << (r)) | (x1 >> (32 - (r))); x1 ^= x0; }
    TFRND(13) TFRND(15) TFRND(26) TFRND(6)
    x0 += ks1; x1 += ks2 + 1u;
    TFRND(17) TFRND(29) TFRND(16) TFRND(24)
    x0 += ks2; x1 += ks0 + 2u;
    TFRND(13) TFRND(15) TFRND(26) TFRND(6)
    x0 += ks0; x1 += ks1 + 3u;
    TFRND(17) TFRND(29) TFRND(16) TFRND(24)
    x0 += ks1; x1 += ks2 + 4u;
    TFRND(13) TFRND(15) TFRND(26) TFRND(6)
    x0 += ks2; x1 += ks0 + 5u;
#undef TFRND
    o0 = x0; o1 = x1;
}

// partitionable-mode bits for flat index m (hi32 = 0): o0 ^ o1
__device__ __forceinline__ uint32_t bits_partitionable(uint32_t m) {
    uint32_t o0, o1;
    tf2x32(0u, m, o0, o1);
    return o0 ^ o1;
}

// jax uniform: f = bitcast((bits>>9)|0x3f800000) - 1; u = max(1e-9, f*(1-1e-9)+1e-9)
__device__ __forceinline__ float bits_to_u(uint32_t w) {
    float f = __uint_as_float((w >> 9) | 0x3f800000u) - 1.0f;
    const float mn = 1e-9f;
    return fmaxf(mn, f * (1.0f - mn) + mn);
}

// ---------------- reductions (1024-thread block, 16 waves) ----------------
__device__ __forceinline__ double wred(double v) {
#pragma unroll
    for (int s = 32; s > 0; s >>= 1) v += __shfl_down(v, s, 64);
    return v;
}

__device__ __forceinline__ double blk_red(double v, double* red16) {
    v = wred(v);
    const int wid = threadIdx.x >> 6, lane = threadIdx.x & 63;
    if (lane == 0) red16[wid] = v;
    __syncthreads();
    double r = 0.0;
#pragma unroll
    for (int i = 0; i < 16; ++i) r += red16[i];
    __syncthreads();
    return r;
}

// ---------------- k-split matmul partial: 1024 threads = O outs x C chunks ----
template<int K, int O>
__device__ __forceinline__ double mm(const float* __restrict__ W,
                                     const float* __restrict__ vin,
                                     double* __restrict__ dpart, int t)
{
    constexpr int C = 1024 / O;
    constexpr int KC = (K + C - 1) / C;
    constexpr int LOGO = (O == 256) ? 8 : 7;
    const int out = t & (O - 1);
    const int c = t >> LOGO;
    const int k0 = c * KC;
    double a0 = 0.0, a1 = 0.0;
#pragma unroll
    for (int i = 0; i < KC; i += 2) {
        const int k = k0 + i;
        if ((K % C == 0) || k < K)
            a0 = fma((double)vin[k], (double)W[k * O + out], a0);
        if ((i + 1 < KC) && ((K % C == 0) || (k + 1 < K)))
            a1 = fma((double)vin[k + 1], (double)W[(k + 1) * O + out], a1);
    }
    dpart[t] = a0 + a1;
    __syncthreads();
    double r = 0.0;
    if (t < O) {
#pragma unroll
        for (int cc = 0; cc < C; ++cc) r += dpart[t + cc * O];
    }
    __syncthreads();   // dpart safely reusable after return
    return r;
}

// LayerNorm over O values (value v held by threads t<O), returns normalized r
template<int O>
__device__ __forceinline__ float ln_norm(float v, bool act, double* red16) {
    double s = blk_red(act ? (double)v : 0.0, red16);
    float m = (float)s * (1.0f / (float)O);
    float d = act ? (v - m) : 0.0f;
    double s2 = blk_red(act ? (double)(d * d) : 0.0, red16);
    float var = (float)s2 * (1.0f / (float)O);
    return d / sqrtf(var + 1e-5f);
}

__global__ __launch_bounds__(1024) void logits_kernel(
    const float* __restrict__ x, const float* __restrict__ st,
    const float* __restrict__ ipw, const float* __restrict__ ipb,
    const float* __restrict__ ipg, const float* __restrict__ ipbb,
    const float* __restrict__ drw, const float* __restrict__ drb,
    const float* __restrict__ drg, const float* __restrict__ drbb,
    const float* __restrict__ r1w, const float* __restrict__ r1b,
    const float* __restrict__ r2w, const float* __restrict__ r2b,
    const float* __restrict__ n1g, const float* __restrict__ n1b,
    const float* __restrict__ n2g, const float* __restrict__ n2b,
    const float* __restrict__ e1w, const float* __restrict__ e1b,
    const float* __restrict__ eg,  const float* __restrict__ eb,
    const float* __restrict__ e2w, const float* __restrict__ e2b,
    float* __restrict__ out_logits)
{
    __shared__ float V0[H2N];
    __shared__ float V1[H2N];
    __shared__ double dpart[1024];
    __shared__ double red16[16];
    const int t = threadIdx.x;
    const int b = blockIdx.x;

    if (t < LATN) V0[t] = x[b * LATN + t];
    else if (t < ZN) V0[t] = st[b * STATSN + (t - LATN)];
    __syncthreads();

    // ---- input_proj: [71] -> relu -> LN(256) -> V1
    {
        double acc = mm<ZN, H2N>(ipw, V0, dpart, t);
        bool act = t < H2N;
        float v = act ? fmaxf((float)acc + ipb[t], 0.0f) : 0.0f;
        float r = ln_norm<H2N>(v, act, red16);
        if (act) V1[t] = r * ipg[t] + ipbb[t];
    }
    __syncthreads();

    // ---- dim_reduce: [256]->[128], relu, LN -> V0[0..127]
    {
        double acc = mm<H2N, HN>(drw, V1, dpart, t);
        bool act = t < HN;
        float v = act ? fmaxf((float)acc + drb[t], 0.0f) : 0.0f;
        float r = ln_norm<HN>(v, act, red16);
        if (act) V0[t] = r * drg[t] + drbb[t];
    }
    __syncthreads();

    // ---- residual blocks: h = h + 0.1*(mlp(h) + h)
    for (int l = 0; l < 2; ++l) {
        const float* w1 = r1w + l * HN * HN;
        const float* b1 = r1b + l * HN;
        const float* w2 = r2w + l * HN * HN;
        const float* b2 = r2b + l * HN;
        const float* g1 = n1g + l * HN;
        const float* c1 = n1b + l * HN;
        const float* g2 = n2g + l * HN;
        const float* c2 = n2b + l * HN;
        bool act = t < HN;
        float hval = act ? V0[t] : 0.0f;
        // LN1
        {
            float r = ln_norm<HN>(hval, act, red16);
            if (act) V1[t] = r * g1[t] + c1[t];
        }
        __syncthreads();
        // lin1 + relu + LN2
        {
            double acc = mm<HN, HN>(w1, V1, dpart, t);
            float rr = act ? fmaxf((float)acc + b1[t], 0.0f) : 0.0f;
            float r = ln_norm<HN>(rr, act, red16);
            __syncthreads();           // all mm reads of V1 done (covered) + LN done
            if (act) V1[t] = r * g2[t] + c2[t];
        }
        __syncthreads();
        // lin2
        {
            double acc = mm<HN, HN>(w2, V1, dpart, t);
            if (act) {
                float r2o = (float)acc + b2[t];
                V0[t] = hval + 0.1f * (r2o + hval);
            }
        }
        __syncthreads();
    }

    // ---- attention uniform (1/256, exact) + edge MLP on [hf, hf]
    {
        bool act = t < HN;
        if (act) {
            float hf = V0[t] * 0.00390625f;
            V1[t] = hf;
            V1[HN + t] = hf;
        }
        __syncthreads();
        double acc = mm<H2N, HN>(e1w, V1, dpart, t);
        float ev = act ? fmaxf((float)acc + e1b[t], 0.0f) : 0.0f;
        float r = ln_norm<HN>(ev, act, red16);
        __syncthreads();
        if (act) V0[t] = r * eg[t] + eb[t];
        __syncthreads();
    }

    // ---- e2: [128]->[2]; 256 threads: out=t&1, c=t>>1 (parity-preserving reduce)
    {
        if (t < 256) {
            const int out = t & 1, c = t >> 1;
            double p = (double)V0[c] * (double)e2w[c * 2 + out];
#pragma unroll
            for (int s = 32; s > 1; s >>= 1) p += __shfl_down(p, s, 64);
            const int wid = t >> 6, lane = t & 63;
            if (lane < 2) dpart[wid * 2 + lane] = p;
        }
        __syncthreads();
        if (t < 2) {
            double acc = 0.0;
#pragma unroll
            for (int c = 0; c < 4; ++c) acc += dpart[c * 2 + t];
            out_logits[b * 2 + t] = (float)acc + e2b[t];
        }
    }
}

// ---------------- per-pair gumbel decisions + scatter ----------------
__device__ __forceinline__ int rowbase(int i) { return (i * (2 * NNODE - 1 - i)) >> 1; }

__global__ __launch_bounds__(256) void edges_kernel(const float* __restrict__ lg,
                                                    const float* __restrict__ tptr,
                                                    float* __restrict__ out)
{
    int q = blockIdx.x * blockDim.x + threadIdx.x;
    if (q >= NQ) return;
    // diagonal zeros (poison-safe: every output element is written each call)
    if (q < BN * NNODE) {
        int bb = q >> 8, ii = q & 255;
        out[(bb << 16) | (ii << 8) | ii] = 0.0f;
    }
    float temp = fminf(fmaxf(tptr[0], 0.1f), 2.0f);

    int b = q / NPAIR;
    int p = q - b * NPAIR;
    // decode upper-triangular (i,j) from linear pair index p
    double disc = 261121.0 - 8.0 * (double)p;  // 511^2 - 8p
    int i = (int)((511.0 - sqrt(disc)) * 0.5);
    if (i < 0) i = 0;
    if (i > NNODE - 2) i = NNODE - 2;
    while (rowbase(i + 1) <= p) ++i;
    while (rowbase(i) > p) --i;
    int j = p - rowbase(i) + i + 1;

    uint32_t w0 = bits_partitionable((uint32_t)(2 * q));
    uint32_t w1 = bits_partitionable((uint32_t)(2 * q + 1));

    float u0 = bits_to_u(w0), u1 = bits_to_u(w1);
    float g0 = (float)(-log(-log((double)u0)));
    float g1 = (float)(-log(-log((double)u1)));
    float l0 = lg[2 * b], l1 = lg[2 * b + 1];
    float A0 = (l0 + g0) / temp, A1 = (l1 + g1) / temp;
    float mx = fmaxf(A0, A1);
    float e0 = expf(A0 - mx), e1 = expf(A1 - mx);
    float ssum = e0 + e1;
    float y0 = e0 / ssum, y1 = e1 / ssum;
    float xe = (y0 >= y1) ? 1.0f : 0.0f;
    out[(b << 16) | (i << 8) | j] = xe;
    out[(b << 16) | (j << 8) | i] = xe;
}

extern "C" void kernel_launch(void* const* d_in, const int* in_sizes, int n_in,
                              void* d_out, int out_size, void* d_ws, size_t ws_size,
                              hipStream_t stream)
{
    const float* x    = (const float*)d_in[0];
    const float* st   = (const float*)d_in[1];
    const float* ipw  = (const float*)d_in[2];
    const float* ipb  = (const float*)d_in[3];
    const float* ipg  = (const float*)d_in[4];
    const float* ipbb = (const float*)d_in[5];
    const float* drw  = (const float*)d_in[6];
    const float* drb  = (const float*)d_in[7];
    const float* drg  = (const float*)d_in[8];
    const float* drbb = (const float*)d_in[9];
    const float* r1w  = (const float*)d_in[10];
    const float* r1b  = (const float*)d_in[11];
    const float* r2w  = (const float*)d_in[12];
    const float* r2b  = (const float*)d_in[13];
    const float* n1g  = (const float*)d_in[14];
    const float* n1b  = (const float*)d_in[15];
    const float* n2g  = (const float*)d_in[16];
    const float* n2b  = (const float*)d_in[17];
    // d_in[18] attn_w, d_in[19] attn_b: unused (softmax over identical nodes is uniform)
    const float* e1w  = (const float*)d_in[20];
    const float* e1b  = (const float*)d_in[21];
    const float* eg   = (const float*)d_in[22];
    const float* eb   = (const float*)d_in[23];
    const float* e2w  = (const float*)d_in[24];
    const float* e2b  = (const float*)d_in[25];
    const float* temp = (const float*)d_in[26];
    float* out = (float*)d_out;
    float* lg  = (float*)d_ws;   // 32 floats: per-batch logits

    hipLaunchKernelGGL(logits_kernel, dim3(BN), dim3(1024), 0, stream,
        x, st, ipw, ipb, ipg, ipbb, drw, drb, drg, drbb,
        r1w, r1b, r2w, r2b, n1g, n1b, n2g, n2b,
        e1w, e1b, eg, eb, e2w, e2b, lg);
    hipLaunchKernelGGL(edges_kernel, dim3((NQ + 255) / 256), dim3(256), 0, stream,
        lg, temp, out);
}

// Round 4
// 35.068 us; speedup vs baseline: 1.4825x; 1.2403x over previous
//
#include <hip/hip_runtime.h>
#include <stdint.h>
#include <math.h>

#define BN 16
#define LATN 64
#define STATSN 7
#define ZN 71
#define HN 128
#define H2N 256
#define NNODE 256
#define NPAIR 32640            // N*(N-1)/2
#define NQ 522240              // BN*NPAIR

// ---------------- Threefry-2x32, 20 rounds, key = (0, 42) ----------------
__device__ __forceinline__ void tf2x32(uint32_t x0, uint32_t x1,
                                       uint32_t& o0, uint32_t& o1) {
    const uint32_t ks0 = 0u, ks1 = 42u, ks2 = 0x1BD11BF0u;  // 0^42^0x1BD11BDA
    x0 += ks0; x1 += ks1;
#define TFRND(r) { x0 += x1; x1 = (x1 << (r)) | (x1 >> (32 - (r))); x1 ^= x0; }
    TFRND(13) TFRND(15) TFRND(26) TFRND(6)
    x0 += ks1; x1 += ks2 + 1u;
    TFRND(17) TFRND(29) TFRND(16) TFRND(24)
    x0 += ks2; x1 += ks0 + 2u;
    TFRND(13) TFRND(15) TFRND(26) TFRND(6)
    x0 += ks0; x1 += ks1 + 3u;
    TFRND(17) TFRND(29) TFRND(16) TFRND(24)
    x0 += ks1; x1 += ks2 + 4u;
    TFRND(13) TFRND(15) TFRND(26) TFRND(6)
    x0 += ks2; x1 += ks0 + 5u;
#undef TFRND
    o0 = x0; o1 = x1;
}

__device__ __forceinline__ uint32_t bits_partitionable(uint32_t m) {
    uint32_t o0, o1;
    tf2x32(0u, m, o0, o1);
    return o0 ^ o1;
}

__device__ __forceinline__ float bits_to_u(uint32_t w) {
    float f = __uint_as_float((w >> 9) | 0x3f800000u) - 1.0f;
    const float mn = 1e-9f;
    return fmaxf(mn, f * (1.0f - mn) + mn);
}

// ---------------- register-resident weight slice ----------------
// 1024 threads = O outputs x C k-chunks; each thread holds KC weights in regs.
template<int K, int O>
struct WSlice {
    static constexpr int C    = 1024 / O;
    static constexpr int KC   = (K + C - 1) / C;
    static constexpr int LOGO = (O == 256) ? 8 : 7;
    float w[KC];
    __device__ __forceinline__ void load(const float* __restrict__ W, int t) {
        const int out = t & (O - 1);
        const int k0 = (t >> LOGO) * KC;
#pragma unroll
        for (int i = 0; i < KC; ++i) {
            const int k = k0 + i;
            w[i] = ((K % C == 0) || k < K) ? W[k * O + out] : 0.0f;
        }
    }
    // identical fma pairing + summation order to the verified round-3 mm()
    __device__ __forceinline__ double dot(const float* __restrict__ vin, int t) const {
        const int k0 = (t >> LOGO) * KC;
        double a0 = 0.0, a1 = 0.0;
#pragma unroll
        for (int i = 0; i < KC; i += 2) {
            a0 = fma((double)vin[k0 + i], (double)w[i], a0);
            if (i + 1 < KC) a1 = fma((double)vin[k0 + i + 1], (double)w[i + 1], a1);
        }
        return a0 + a1;
    }
    // edge_in = [hf, hf]: read vin[(k)&127] (no LDS duplication barrier)
    __device__ __forceinline__ double dot_mask127(const float* __restrict__ vin, int t) const {
        const int k0 = (t >> LOGO) * KC;
        double a0 = 0.0, a1 = 0.0;
#pragma unroll
        for (int i = 0; i < KC; i += 2) {
            a0 = fma((double)vin[(k0 + i) & 127], (double)w[i], a0);
            if (i + 1 < KC) a1 = fma((double)vin[(k0 + i + 1) & 127], (double)w[i + 1], a1);
        }
        return a0 + a1;
    }
};

// fused LayerNorm stats (single pass: sum + sumsq reduced as a pair)
template<int O>
__device__ __forceinline__ float ln_apply(float v, int t, double* red) {
    constexpr int NW = O / 64;
    double a = (t < O) ? (double)v : 0.0;
    double q = a * a;
#pragma unroll
    for (int s = 32; s > 0; s >>= 1) {
        a += __shfl_down(a, s, 64);
        q += __shfl_down(q, s, 64);
    }
    const int wid = t >> 6, lane = t & 63;
    if (wid < NW && lane == 0) { red[2 * wid] = a; red[2 * wid + 1] = q; }
    __syncthreads();
    double sa = 0.0, sq = 0.0;
#pragma unroll
    for (int i = 0; i < NW; ++i) { sa += red[2 * i]; sq += red[2 * i + 1]; }
    const double m = sa * (1.0 / (double)O);
    const double var = sq * (1.0 / (double)O) - m * m;
    const double rs = 1.0 / sqrt(var + 1e-5);
    return (float)(((double)v - m) * rs);
}

__global__ __launch_bounds__(1024) void logits_kernel(
    const float* __restrict__ x, const float* __restrict__ st,
    const float* __restrict__ ipw, const float* __restrict__ ipb,
    const float* __restrict__ ipg, const float* __restrict__ ipbb,
    const float* __restrict__ drw, const float* __restrict__ drb,
    const float* __restrict__ drg, const float* __restrict__ drbb,
    const float* __restrict__ r1w, const float* __restrict__ r1b,
    const float* __restrict__ r2w, const float* __restrict__ r2b,
    const float* __restrict__ n1g, const float* __restrict__ n1b,
    const float* __restrict__ n2g, const float* __restrict__ n2b,
    const float* __restrict__ e1w, const float* __restrict__ e1b,
    const float* __restrict__ eg,  const float* __restrict__ eb,
    const float* __restrict__ e2w, const float* __restrict__ e2b,
    float* __restrict__ out_logits)
{
    __shared__ float V0[H2N];
    __shared__ float V1[H2N];
    __shared__ double dpart[1024];
    __shared__ double red[8];
    const int t = threadIdx.x;
    const int b = blockIdx.x;
    const int t255 = t & 255, t127 = t & 127;

    // -------- prologue: issue weight/bias prefetches, stage z --------
    WSlice<ZN, H2N> w_ip;  w_ip.load(ipw, t);
    const float ipb_r  = ipb[t255],  ipg_r = ipg[t255],  ipbb_r = ipbb[t255];
    const float drb_r  = drb[t127],  drg_r = drg[t127],  drbb_r = drbb[t127];
    const float b1a = r1b[t127],       g1a = n1g[t127],       c1a = n1b[t127];
    const float g2a = n2g[t127],       c2a = n2b[t127],       b2a = r2b[t127];
    const float b1b = r1b[128 + t127], g1b = n1g[128 + t127], c1b = n1b[128 + t127];
    const float g2b = n2g[128 + t127], c2b = n2b[128 + t127], b2b = r2b[128 + t127];
    const float e1b_r = e1b[t127], eg_r = eg[t127], eb_r = eb[t127];
    const float e2w_r = e2w[t255];  // e2w[(t>>1)*2 + (t&1)] == e2w[t]

    if (t < LATN)      V0[t] = x[b * LATN + t];
    else if (t < ZN)   V0[t] = st[b * STATSN + (t - LATN)];
    else if (t < H2N)  V0[t] = 0.0f;   // zero-pad so padded w entries multiply 0, not junk
    __syncthreads();

    // -------- input_proj: [71]->relu->LN(256) -> V1 --------
    WSlice<H2N, HN> w_dr;  w_dr.load(drw, t);   // prefetch next phase
    {
        double acc = w_ip.dot(V0, t);
        dpart[t] = acc;
        __syncthreads();
        float v = 0.0f;
        const bool act = t < H2N;
        if (act) {
            double ca = 0.0;
#pragma unroll
            for (int cc = 0; cc < WSlice<ZN, H2N>::C; ++cc) ca += dpart[t + cc * H2N];
            v = fmaxf((float)ca + ipb_r, 0.0f);
        }
        float r = ln_apply<H2N>(v, t, red);
        if (act) V1[t] = r * ipg_r + ipbb_r;
    }
    __syncthreads();

    // -------- dim_reduce: [256]->[128], relu, LN -> V0 --------
    WSlice<HN, HN> w_r1a;  w_r1a.load(r1w, t);   // prefetch
    {
        double acc = w_dr.dot(V1, t);
        dpart[t] = acc;
        __syncthreads();
        float v = 0.0f;
        const bool act = t < HN;
        if (act) {
            double ca = 0.0;
#pragma unroll
            for (int cc = 0; cc < WSlice<H2N, HN>::C; ++cc) ca += dpart[t + cc * HN];
            v = fmaxf((float)ca + drb_r, 0.0f);
        }
        float r = ln_apply<HN>(v, t, red);
        if (act) V0[t] = r * drg_r + drbb_r;
    }
    __syncthreads();

    // -------- residual block 0 --------
    WSlice<HN, HN> w_r2a;  w_r2a.load(r2w, t);   // prefetch
    float hval = (t < HN) ? V0[t] : 0.0f;
    {   // LN1
        float r = ln_apply<HN>(hval, t, red);
        if (t < HN) V1[t] = r * g1a + c1a;
    }
    __syncthreads();
    WSlice<HN, HN> w_r1b;  w_r1b.load(r1w + HN * HN, t);   // prefetch
    {   // lin1 + relu + LN2
        double acc = w_r1a.dot(V1, t);
        dpart[t] = acc;
        __syncthreads();
        float v = 0.0f;
        if (t < HN) {
            double ca = 0.0;
#pragma unroll
            for (int cc = 0; cc < WSlice<HN, HN>::C; ++cc) ca += dpart[t + cc * HN];
            v = fmaxf((float)ca + b1a, 0.0f);
        }
        float r = ln_apply<HN>(v, t, red);
        if (t < HN) V1[t] = r * g2a + c2a;
    }
    __syncthreads();
    WSlice<HN, HN> w_r2b;  w_r2b.load(r2w + HN * HN, t);   // prefetch
    {   // lin2 + residual
        double acc = w_r2a.dot(V1, t);
        dpart[t] = acc;
        __syncthreads();
        if (t < HN) {
            double ca = 0.0;
#pragma unroll
            for (int cc = 0; cc < WSlice<HN, HN>::C; ++cc) ca += dpart[t + cc * HN];
            float r2o = (float)ca + b2a;
            V0[t] = hval + 0.1f * (r2o + hval);
        }
    }
    __syncthreads();

    // -------- residual block 1 --------
    hval = (t < HN) ? V0[t] : 0.0f;
    {   // LN1
        float r = ln_apply<HN>(hval, t, red);
        if (t < HN) V1[t] = r * g1b + c1b;
    }
    __syncthreads();
    WSlice<H2N, HN> w_e1;  w_e1.load(e1w, t);   // prefetch edge MLP
    {   // lin1 + relu + LN2
        double acc = w_r1b.dot(V1, t);
        dpart[t] = acc;
        __syncthreads();
        float v = 0.0f;
        if (t < HN) {
            double ca = 0.0;
#pragma unroll
            for (int cc = 0; cc < WSlice<HN, HN>::C; ++cc) ca += dpart[t + cc * HN];
            v = fmaxf((float)ca + b1b, 0.0f);
        }
        float r = ln_apply<HN>(v, t, red);
        if (t < HN) V1[t] = r * g2b + c2b;
    }
    __syncthreads();
    {   // lin2 + residual
        double acc = w_r2b.dot(V1, t);
        dpart[t] = acc;
        __syncthreads();
        if (t < HN) {
            double ca = 0.0;
#pragma unroll
            for (int cc = 0; cc < WSlice<HN, HN>::C; ++cc) ca += dpart[t + cc * HN];
            float r2o = (float)ca + b2b;
            V0[t] = hval + 0.1f * (r2o + hval);
        }
    }
    __syncthreads();

    // -------- attention uniform (exact 1/256) + edge MLP e1 --------
    {
        // edge_in[k] = (h*(1/256))[k & 127]; scale applied after the dot (exact pow2)
        double acc = w_e1.dot_mask127(V0, t) * 0.00390625;
        dpart[t] = acc;
        __syncthreads();
        float v = 0.0f;
        if (t < HN) {
            double ca = 0.0;
#pragma unroll
            for (int cc = 0; cc < WSlice<H2N, HN>::C; ++cc) ca += dpart[t + cc * HN];
            v = fmaxf((float)ca + e1b_r, 0.0f);
        }
        float r = ln_apply<HN>(v, t, red);
        if (t < HN) V0[t] = r * eg_r + eb_r;
    }
    __syncthreads();

    // -------- e2: [128]->[2] (identical arithmetic to round 3) --------
    {
        if (t < 256) {
            const int c = t >> 1;
            double p = (double)V0[c] * (double)e2w_r;
#pragma unroll
            for (int s = 32; s > 1; s >>= 1) p += __shfl_down(p, s, 64);
            const int wid = t >> 6, lane = t & 63;
            if (lane < 2) dpart[wid * 2 + lane] = p;
        }
        __syncthreads();
        if (t < 2) {
            double acc = 0.0;
#pragma unroll
            for (int c2 = 0; c2 < 4; ++c2) acc += dpart[c2 * 2 + t];
            out_logits[b * 2 + t] = (float)acc + e2b[t];
        }
    }
}

// ---------------- per-pair gumbel decisions + scatter ----------------
__device__ __forceinline__ int rowbase(int i) { return (i * (2 * NNODE - 1 - i)) >> 1; }

__global__ __launch_bounds__(256) void edges_kernel(const float* __restrict__ lg,
                                                    const float* __restrict__ tptr,
                                                    float* __restrict__ out)
{
    int q = blockIdx.x * blockDim.x + threadIdx.x;
    if (q >= NQ) return;
    // diagonal zeros (poison-safe: every output element is written each call)
    if (q < BN * NNODE) {
        int bb = q >> 8, ii = q & 255;
        out[(bb << 16) | (ii << 8) | ii] = 0.0f;
    }
    float temp = fminf(fmaxf(tptr[0], 0.1f), 2.0f);

    int b = q / NPAIR;
    int p = q - b * NPAIR;
    double disc = 261121.0 - 8.0 * (double)p;  // 511^2 - 8p
    int i = (int)((511.0 - sqrt(disc)) * 0.5);
    if (i < 0) i = 0;
    if (i > NNODE - 2) i = NNODE - 2;
    while (rowbase(i + 1) <= p) ++i;
    while (rowbase(i) > p) --i;
    int j = p - rowbase(i) + i + 1;

    uint32_t w0 = bits_partitionable((uint32_t)(2 * q));
    uint32_t w1 = bits_partitionable((uint32_t)(2 * q + 1));

    float u0 = bits_to_u(w0), u1 = bits_to_u(w1);
    float g0 = (float)(-log(-log((double)u0)));
    float g1 = (float)(-log(-log((double)u1)));
    float l0 = lg[2 * b], l1 = lg[2 * b + 1];
    float A0 = (l0 + g0) / temp, A1 = (l1 + g1) / temp;
    float mx = fmaxf(A0, A1);
    float e0 = expf(A0 - mx), e1 = expf(A1 - mx);
    float ssum = e0 + e1;
    float y0 = e0 / ssum, y1 = e1 / ssum;
    float xe = (y0 >= y1) ? 1.0f : 0.0f;
    out[(b << 16) | (i << 8) | j] = xe;
    out[(b << 16) | (j << 8) | i] = xe;
}

extern "C" void kernel_launch(void* const* d_in, const int* in_sizes, int n_in,
                              void* d_out, int out_size, void* d_ws, size_t ws_size,
                              hipStream_t stream)
{
    const float* x    = (const float*)d_in[0];
    const float* st   = (const float*)d_in[1];
    const float* ipw  = (const float*)d_in[2];
    const float* ipb  = (const float*)d_in[3];
    const float* ipg  = (const float*)d_in[4];
    const float* ipbb = (const float*)d_in[5];
    const float* drw  = (const float*)d_in[6];
    const float* drb  = (const float*)d_in[7];
    const float* drg  = (const float*)d_in[8];
    const float* drbb = (const float*)d_in[9];
    const float* r1w  = (const float*)d_in[10];
    const float* r1b  = (const float*)d_in[11];
    const float* r2w  = (const float*)d_in[12];
    const float* r2b  = (const float*)d_in[13];
    const float* n1g  = (const float*)d_in[14];
    const float* n1b  = (const float*)d_in[15];
    const float* n2g  = (const float*)d_in[16];
    const float* n2b  = (const float*)d_in[17];
    // d_in[18] attn_w, d_in[19] attn_b: unused (softmax over identical nodes is uniform)
    const float* e1w  = (const float*)d_in[20];
    const float* e1b  = (const float*)d_in[21];
    const float* eg   = (const float*)d_in[22];
    const float* eb   = (const float*)d_in[23];
    const float* e2w  = (const float*)d_in[24];
    const float* e2b  = (const float*)d_in[25];
    const float* temp = (const float*)d_in[26];
    float* out = (float*)d_out;
    float* lg  = (float*)d_ws;   // 32 floats: per-batch logits

    hipLaunchKernelGGL(logits_kernel, dim3(BN), dim3(1024), 0, stream,
        x, st, ipw, ipb, ipg, ipbb, drw, drb, drg, drbb,
        r1w, r1b, r2w, r2b, n1g, n1b, n2g, n2b,
        e1w, e1b, eg, eb, e2w, e2b, lg);
    hipLaunchKernelGGL(edges_kernel, dim3((NQ + 255) / 256), dim3(256), 0, stream,
        lg, temp, out);
}